// Round 17
// baseline (129.847 us; speedup 1.0000x reference)
//
#include <hip/hip_runtime.h>

#define NEGF -3.402823466e38f
#define MASKED_F -3.38953139e38f   // most-negative finite bf16 value, used as masked sentinel
#define LOG2E 1.44269504088896f
#define DEFER_THR 8.0f

typedef __attribute__((ext_vector_type(8))) short bf16x8;
typedef __attribute__((ext_vector_type(4))) float f32x4;
typedef __attribute__((ext_vector_type(4))) unsigned short u16x4;
typedef __attribute__((ext_vector_type(4))) int i32x4;
typedef __attribute__((ext_vector_type(2))) unsigned int u32x2;

__device__ __forceinline__ unsigned short f2bf(float f) {
  unsigned u = __builtin_bit_cast(unsigned, f);
  u += 0x7fffu + ((u >> 16) & 1u);
  return (unsigned short)(u >> 16);
}

#define GLOAD_LDS16(gsrc, ldst)                                                     \
  __builtin_amdgcn_global_load_lds(                                                 \
      (const __attribute__((address_space(1))) void*)(gsrc),                        \
      (__attribute__((address_space(3))) void*)(ldst), 16, 0, 0)

// ws layout in ushort units
#define OFF_QH  0u
#define OFF_KH  2097152u
#define OFF_W   4194304u      // 4 x 65536 (Wq,Wk,Wv,Wo) bf16
#define OFF_QP  4456448u      // [B,H,S,D] bf16, pre-scaled by log2e/8
#define OFF_KP  6553600u      // [B,H,S,D] bf16
#define OFF_VT  8650752u      // [B,H,D,S] bf16 (V transposed)
#define OFF_ATT 10747904u     // [B,S,256] bf16
#define OFF_BM  12845056u     // [B][32][2048] u64 align bitmap (2 MB = 1048576 ushorts)
#define OFF_FLAG 13893632u    // int flag: amask has any nonzero
#define USHORT_USED 13893664u // end (64B-aligned past flag)

// ---------------- f32 -> bf16 conversion of inputs (+ flag reset) ----------------
__global__ __launch_bounds__(256) void k_convert(
    const float* __restrict__ qh, const float* __restrict__ kh,
    const float* __restrict__ w0, const float* __restrict__ w1,
    const float* __restrict__ w2, const float* __restrict__ w3,
    unsigned short* __restrict__ dst, int* __restrict__ flag) {
  int v = blockIdx.x * 256 + threadIdx.x;   // vector-of-4 index
  if (v == 0) *flag = 0;                    // reset before k_maskaux (stream-ordered)
  const float* src;
  if (v < 524288)       src = qh + (size_t)v * 4;
  else if (v < 1048576) src = kh + ((size_t)v - 524288) * 4;
  else {
    int t = v - 1048576;                    // 0 .. 65535
    int which = t >> 14;
    const float* w = (which == 0) ? w0 : (which == 1) ? w1 : (which == 2) ? w2 : w3;
    src = w + (size_t)(t & 16383) * 4;
  }
  f32x4 x = *(const f32x4*)src;
  u16x4 o;
  o[0] = f2bf(x[0]); o[1] = f2bf(x[1]); o[2] = f2bf(x[2]); o[3] = f2bf(x[3]);
  *(u16x4*)(dst + (size_t)v * 4) = o;
}

// ---------------- fused align bitpack (vectorized) + amask nonzero check ----------------
// blocks 0..255: each thread packs 4 consecutive q columns via i32x4 row loads
//   (1 KB contiguous per wave-instruction per k-row).
// blocks 256..1279: OR-reduce amask, set flag if any nonzero.
__global__ __launch_bounds__(256) void k_maskaux(const int* __restrict__ al,
    const float* __restrict__ am, unsigned long long* __restrict__ bm,
    int* __restrict__ flag) {
  int bid = blockIdx.x;
  if (bid < 256) {
    int t = bid * 256 + threadIdx.x;        // 0..65535
    int q4 = t & 511;                       // q = q4*4 .. q4*4+3
    int k64 = (t >> 9) & 31;
    int b = t >> 14;
    const int* base = al + ((size_t)(b * 2048 + k64 * 64)) * 2048 + q4 * 4;
    unsigned long long w0 = 0, w1 = 0, w2 = 0, w3 = 0;
#pragma unroll
    for (int k = 0; k < 64; ++k) {
      i32x4 v = *(const i32x4*)(base + (size_t)k * 2048);
      unsigned long long bit = 1ull << k;
      if (v[0] != 0) w0 |= bit;
      if (v[1] != 0) w1 |= bit;
      if (v[2] != 0) w2 |= bit;
      if (v[3] != 0) w3 |= bit;
    }
    unsigned long long* o = bm + ((size_t)b * 65536 + k64 * 2048 + q4 * 4);
    o[0] = w0; o[1] = w1; o[2] = w2; o[3] = w3;
  } else {
    const f32x4* p = (const f32x4*)am;      // 4,194,304 f32x4 total
    size_t tid = (size_t)(bid - 256) * 256 + threadIdx.x;   // 0..262143
    unsigned nz = 0;
#pragma unroll
    for (int j = 0; j < 16; ++j) {
      f32x4 v = p[tid + (size_t)j * 262144];
      nz |= (v[0] != 0.f) | (v[1] != 0.f) | (v[2] != 0.f) | (v[3] != 0.f);
    }
    if (__any(nz)) {
      if ((threadIdx.x & 63) == 0) atomicOr(flag, 1);
    }
  }
}

// ---------------- QKV projections ----------------
__global__ __launch_bounds__(256) void k_proj(unsigned short* __restrict__ ws) {
  int bid = blockIdx.x;
  int mat = bid / 512;            // 0=Q 1=K 2=V
  int rem = bid - mat * 512;
  int mt = rem >> 2, nt = rem & 3;
  int tid = threadIdx.x, w = tid >> 6, lane = tid & 63;
  int l15 = lane & 15, l4 = lane >> 4;

  const unsigned short* X = ws + (mat == 0 ? OFF_QH : OFF_KH);
  const unsigned short* W = ws + OFF_W + (size_t)mat * 65536;

  int i0 = mt * 64 + w * 16;
  int arow = i0 + l15;
  int koff = l4 * 8;

  f32x4 acc[4] = {};
  for (int ks = 0; ks < 8; ++ks) {
    bf16x8 a = *(const bf16x8*)(X + (size_t)arow * 256 + ks * 32 + koff);
#pragma unroll
    for (int ct = 0; ct < 4; ++ct) {
      bf16x8 bb = *(const bf16x8*)(W + (size_t)(nt * 64 + ct * 16 + l15) * 256 + ks * 32 + koff);
      acc[ct] = __builtin_amdgcn_mfma_f32_16x16x32_bf16(a, bb, acc[ct], 0, 0, 0);
    }
  }

  unsigned short* Qp = ws + OFF_QP;
  unsigned short* Kp = ws + OFF_KP;
  unsigned short* Vt = ws + OFF_VT;
  int rbase = i0 + l4 * 4;
#pragma unroll
  for (int ct = 0; ct < 4; ++ct) {
#pragma unroll
    for (int r = 0; r < 4; ++r) {
      int row = rbase + r;
      int b = row >> 11, s = row & 2047;
      int d = ct * 16 + l15;
      float v = acc[ct][r];
      if (mat == 0)      Qp[((size_t)(b * 4 + nt) * 2048 + s) * 64 + d] = f2bf(v * (0.125f * LOG2E));
      else if (mat == 1) Kp[((size_t)(b * 4 + nt) * 2048 + s) * 64 + d] = f2bf(v);
      else               Vt[((size_t)(b * 4 + nt) * 64 + d) * 2048 + s] = f2bf(v);
    }
  }
}

// ---------------- fused masked flash attention ----------------
// swapped QK^T: sfr[kt][r] = S[k = kk + kt*16 + l4*4 + r][q = q0 + l15]
// Mask loads issued BEFORE staging loads (vmcnt FIFO); align-mask applied
// AFTER exp2 by zeroing e. XCD-aware bijective block swizzle.
template <int NS>
__global__ __launch_bounds__(256) void k_attn(unsigned short* __restrict__ ws,
    const float* __restrict__ am, const unsigned long long* __restrict__ bm,
    const int* __restrict__ amflag,
    float* __restrict__ po, float* __restrict__ pm, float* __restrict__ pl) {
  constexpr int LOG = (NS == 4) ? 2 : (NS == 2) ? 1 : 0;
  constexpr int SPAN = 2048 / NS;

  __shared__ __align__(16) unsigned short Kb[2][4096];   // [64 krow][64 d] swizzled
  __shared__ __align__(16) unsigned short Vb[2][4096];   // [64 d][64 k] swizzled
  __shared__ __align__(16) unsigned short plds[4][1024]; // per-wave 16x64 P, swizzled

  // XCD swizzle: grid % 8 == 0 (512*NS). Physical p runs on XCD p%8;
  // logical bid = (p%8)*(grid/8) + p/8 gives each XCD a contiguous chunk.
  int cpx = (int)gridDim.x >> 3;
  int bid = ((int)blockIdx.x & 7) * cpx + ((int)blockIdx.x >> 3);

  int sp = bid & (NS - 1);
  int qt = (bid >> LOG) & 31;
  int bh = bid >> (LOG + 5);
  int b = bh >> 2, h = bh & 3;
  int tid = threadIdx.x, w = tid >> 6, lane = tid & 63;
  int l15 = lane & 15, l4 = lane >> 4;
  int q0 = qt * 64 + w * 16;

  const bool hasam = (*amflag != 0);   // wave-uniform

  const unsigned short* Qp = ws + OFF_QP;
  const unsigned short* Kp = ws + OFF_KP + (size_t)bh * 2048 * 64;
  const unsigned short* Vt = ws + OFF_VT + (size_t)bh * 64 * 2048;
  const float* amq = am + ((size_t)(b * 2048 + q0 + l15)) * 2048;     // this lane's q-row
  const unsigned long long* bmq = bm + (size_t)b * 65536 + q0 + l15;  // + k64*2048

  // staging geometry: lane i covers row (c*8 + i>>3), global col chunk (i&7)^(i>>3)
  int srow = lane >> 3;
  int scol = ((lane & 7) ^ srow) * 8;
  int c0 = w * 2;

  bf16x8 qf0 = *(const bf16x8*)(Qp + ((size_t)bh * 2048 + q0 + l15) * 64 + l4 * 8);
  bf16x8 qf1 = *(const bf16x8*)(Qp + ((size_t)bh * 2048 + q0 + l15) * 64 + 32 + l4 * 8);

  f32x4 o[4] = {};
  float mrun = -__builtin_inff();
  float lpart = 0.f;                // per-lane partial sum (this lane's k-subset of row q=l15)
  int s0 = l4 * 4;

  int kk0 = sp * SPAN;
#pragma unroll
  for (int c2 = 0; c2 < 2; ++c2) {
    int c = c0 + c2;
    GLOAD_LDS16(Kp + (size_t)(kk0 + c * 8 + srow) * 64 + scol, &Kb[0][c * 512]);
    GLOAD_LDS16(Vt + (size_t)(c * 8 + srow) * 2048 + kk0 + scol, &Vb[0][c * 512]);
  }
  __syncthreads();

  int cur = 0;
  for (int kk = kk0; kk < kk0 + SPAN; kk += 64) {
    // ---- mask inputs FIRST (oldest in vmcnt FIFO -> consume waits only these) ----
    unsigned long long wbits = bmq[(size_t)(kk >> 6) * 2048];
    f32x4 a0{}, a1{}, a2{}, a3{};
    if (hasam) {
      a0 = *(const f32x4*)(amq + kk + 0 * 16 + s0);
      a1 = *(const f32x4*)(amq + kk + 1 * 16 + s0);
      a2 = *(const f32x4*)(amq + kk + 2 * 16 + s0);
      a3 = *(const f32x4*)(amq + kk + 3 * 16 + s0);
    }
    // ---- stage next tile (stays in flight across whole iteration) ----
    if (kk + 64 < kk0 + SPAN) {
#pragma unroll
      for (int c2 = 0; c2 < 2; ++c2) {
        int c = c0 + c2;
        GLOAD_LDS16(Kp + (size_t)(kk + 64 + c * 8 + srow) * 64 + scol, &Kb[cur ^ 1][c * 512]);
        GLOAD_LDS16(Vt + (size_t)(c * 8 + srow) * 2048 + (kk + 64) + scol, &Vb[cur ^ 1][c * 512]);
      }
    }

    // ---- scores (log2 domain, swapped): S^T = K @ Q^T ----
    f32x4 sfr[4];
    __builtin_amdgcn_s_setprio(1);
#pragma unroll
    for (int kt = 0; kt < 4; ++kt) {
      int row = kt * 16 + l15;
      int sw = l15 & 7;
      bf16x8 k0 = *(const bf16x8*)&Kb[cur][row * 64 + ((l4 ^ sw) * 8)];
      bf16x8 k1 = *(const bf16x8*)&Kb[cur][row * 64 + (((4 + l4) ^ sw) * 8)];
      f32x4 acc = {};
      acc = __builtin_amdgcn_mfma_f32_16x16x32_bf16(k0, qf0, acc, 0, 0, 0);
      acc = __builtin_amdgcn_mfma_f32_16x16x32_bf16(k1, qf1, acc, 0, 0, 0);
      sfr[kt] = acc;
    }
    __builtin_amdgcn_s_setprio(0);

    // ---- amask add (slow path only) ----
    if (hasam) {
#pragma unroll
      for (int kt = 0; kt < 4; ++kt) {
        f32x4 a = (kt == 0) ? a0 : (kt == 1) ? a1 : (kt == 2) ? a2 : a3;
#pragma unroll
        for (int r = 0; r < 4; ++r) sfr[kt][r] = fmaf(a[r], LOG2E, sfr[kt][r]);
      }
    }

    // ---- per-lane row max over UNMASKED scores (valid common M) ----
    float pmax = sfr[0][0];
#pragma unroll
    for (int kt = 0; kt < 4; ++kt)
#pragma unroll
      for (int r = 0; r < 4; ++r) pmax = fmaxf(pmax, sfr[kt][r]);
    pmax = fmaxf(pmax, __shfl_xor(pmax, 16));
    pmax = fmaxf(pmax, __shfl_xor(pmax, 32));

    // ---- defer-max: rescale only when max grew past threshold ----
    if (__any(pmax > mrun + DEFER_THR)) {
      float mnew = fmaxf(mrun, pmax);
      float sfac = exp2f(mrun - mnew);
      mrun = mnew;
      lpart *= sfac;
#pragma unroll
      for (int r = 0; r < 4; ++r) {
        float sf = __shfl(sfac, l4 * 4 + r);
        o[0][r] *= sf; o[1][r] *= sf; o[2][r] *= sf; o[3][r] *= sf;
      }
    }

    // ---- exp2, mask-by-zero, partial sum, P-pack ----
    unsigned blo = (unsigned)wbits, bhi = (unsigned)(wbits >> 32);
    float ls = 0.f;
#pragma unroll
    for (int kt = 0; kt < 4; ++kt) {
      unsigned tbits = ((kt & 2) ? bhi : blo) >> ((kt & 1) ? 16 + s0 : s0);
      float em[4];
#pragma unroll
      for (int r = 0; r < 4; ++r) {
        float e = exp2f(sfr[kt][r] - mrun);
        unsigned keep = 0u - ((tbits >> r) & 1u);   // all-ones or zero
        em[r] = __builtin_bit_cast(float, __builtin_bit_cast(unsigned, e) & keep);
        ls += em[r];
      }
      unsigned lo, hi;
      asm("v_cvt_pk_bf16_f32 %0, %1, %2" : "=v"(lo) : "v"(em[0]), "v"(em[1]));
      asm("v_cvt_pk_bf16_f32 %0, %1, %2" : "=v"(hi) : "v"(em[2]), "v"(em[3]));
      int chunk = kt * 2 + (l4 >> 1);
      int addr = l15 * 64 + (((chunk) ^ (l15 & 7)) << 3) + ((l4 & 1) << 2);
      u32x2 pk; pk[0] = lo; pk[1] = hi;
      *(u32x2*)&plds[w][addr] = pk;
    }
    lpart += ls;

    // ---- PV: O += P @ V from LDS ----
    __builtin_amdgcn_s_setprio(1);
#pragma unroll
    for (int ks = 0; ks < 2; ++ks) {
      int chnk = ks * 4 + l4;
      bf16x8 pa = *(const bf16x8*)&plds[w][l15 * 64 + ((chnk ^ (l15 & 7)) << 3)];
#pragma unroll
      for (int dt = 0; dt < 4; ++dt) {
        int row = dt * 16 + l15;
        bf16x8 vf = *(const bf16x8*)&Vb[cur][row * 64 + (((ks * 4 + l4) ^ (l15 & 7)) * 8)];
        o[dt] = __builtin_amdgcn_mfma_f32_16x16x32_bf16(pa, vf, o[dt], 0, 0, 0);
      }
    }
    __builtin_amdgcn_s_setprio(0);

    __syncthreads();   // drains vmcnt (stage done) + guards buffer swap
    cur ^= 1;
  }

  // ---- epilogue: reduce per-lane partial sums across l4 ----
  float lsum = lpart;
  lsum += __shfl_xor(lsum, 16);
  lsum += __shfl_xor(lsum, 32);

  if constexpr (NS == 1) {
    unsigned short* attnb = ws + OFF_ATT;
#pragma unroll
    for (int r = 0; r < 4; ++r) {
      float inv = 1.0f / __shfl(lsum, l4 * 4 + r);
      int qrow = q0 + l4 * 4 + r;
#pragma unroll
      for (int dt = 0; dt < 4; ++dt)
        attnb[(size_t)(b * 2048 + qrow) * 256 + h * 64 + dt * 16 + l15] = f2bf(o[dt][r] * inv);
    }
  } else {
    float* pob = po + (((size_t)sp * 16 + bh) * 2048) * 64;
#pragma unroll
    for (int r = 0; r < 4; ++r) {
      int qrow = q0 + l4 * 4 + r;
#pragma unroll
      for (int dt = 0; dt < 4; ++dt)
        pob[(size_t)qrow * 64 + dt * 16 + l15] = o[dt][r];
    }
    if (l4 == 0) {
      pm[(size_t)sp * 32768 + bh * 2048 + q0 + l15] = mrun;
      pl[(size_t)sp * 32768 + bh * 2048 + q0 + l15] = lsum;
    }
  }
}

// ---------------- combine K-splits (log2 domain weights) ----------------
template <int NS>
__global__ __launch_bounds__(256) void k_combine(const float* __restrict__ po,
    const float* __restrict__ pm, const float* __restrict__ pl,
    unsigned short* __restrict__ attnb) {
  int t = blockIdx.x * 256 + threadIdx.x;
  int d = t & 63;
  int row = t >> 6;                 // bh*2048 + qrow, 0..32767

  float m[NS], l[NS];
  float M = -__builtin_inff();
#pragma unroll
  for (int sp = 0; sp < NS; ++sp) {
    m[sp] = pm[(size_t)sp * 32768 + row];
    l[sp] = pl[(size_t)sp * 32768 + row];
    M = fmaxf(M, m[sp]);
  }
  float denom = 0.f, acc = 0.f;
#pragma unroll
  for (int sp = 0; sp < NS; ++sp) {
    float wgt = exp2f(m[sp] - M);
    denom += l[sp] * wgt;
    acc += po[((size_t)sp * 32768 + row) * 64 + d] * wgt;
  }
  float val = acc / denom;
  int bh = row >> 11, qrow = row & 2047;
  int b = bh >> 2, h = bh & 3;
  attnb[((size_t)(b * 2048 + qrow)) * 256 + h * 64 + d] = f2bf(val);
}

// ---------------- output projection ----------------
__global__ __launch_bounds__(256) void k_oproj(const unsigned short* __restrict__ ws,
                                               float* __restrict__ out) {
  int bid = blockIdx.x;
  int mt = bid >> 2, nt = bid & 3;
  int tid = threadIdx.x, w = tid >> 6, lane = tid & 63;
  int l15 = lane & 15, l4 = lane >> 4;

  const unsigned short* A = ws + OFF_ATT;
  const unsigned short* W = ws + OFF_W + 3u * 65536u;   // Wo
  int i0 = mt * 64 + w * 16;

  f32x4 acc[4] = {};
  for (int ks = 0; ks < 8; ++ks) {
    bf16x8 a = *(const bf16x8*)(A + (size_t)(i0 + l15) * 256 + ks * 32 + l4 * 8);
#pragma unroll
    for (int ct = 0; ct < 4; ++ct) {
      bf16x8 bb = *(const bf16x8*)(W + (size_t)(nt * 64 + ct * 16 + l15) * 256 + ks * 32 + l4 * 8);
      acc[ct] = __builtin_amdgcn_mfma_f32_16x16x32_bf16(a, bb, acc[ct], 0, 0, 0);
    }
  }
#pragma unroll
  for (int ct = 0; ct < 4; ++ct)
#pragma unroll
    for (int r = 0; r < 4; ++r)
      out[(size_t)(i0 + l4 * 4 + r) * 256 + nt * 64 + ct * 16 + l15] = acc[ct][r];
}

extern "C" void kernel_launch(void* const* d_in, const int* in_sizes, int n_in,
                              void* d_out, int out_size, void* d_ws, size_t ws_size,
                              hipStream_t stream) {
  const float* qh = (const float*)d_in[0];
  const float* kh = (const float*)d_in[1];
  const float* amask = (const float*)d_in[2];
  const int* alignm = (const int*)d_in[3];
  const float* Wq = (const float*)d_in[4];
  const float* Wk = (const float*)d_in[5];
  const float* Wv = (const float*)d_in[6];
  const float* Wo = (const float*)d_in[7];
  float* out = (float*)d_out;
  unsigned short* ws = (unsigned short*)d_ws;
  unsigned long long* bm = (unsigned long long*)(ws + OFF_BM);
  int* amflag = (int*)(ws + OFF_FLAG);

  k_convert<<<4352, 256, 0, stream>>>(qh, kh, Wq, Wk, Wv, Wo, ws, amflag);
  k_maskaux<<<1280, 256, 0, stream>>>(alignm, amask, bm, amflag);
  k_proj<<<1536, 256, 0, stream>>>(ws);

  size_t avail_f = (ws_size > (size_t)USHORT_USED * 2)
                       ? (ws_size - (size_t)USHORT_USED * 2) / 4 : 0;
  auto need = [](int ns) { return (size_t)ns * (2097152 + 65536); };
  int NSv = (avail_f >= need(2)) ? 2 : 1;
  float* po = (float*)(ws + USHORT_USED);
  float* pm = po + (size_t)NSv * 2097152;
  float* pl = pm + (size_t)NSv * 32768;

  if (NSv == 2) {
    k_attn<2><<<1024, 256, 0, stream>>>(ws, amask, bm, amflag, po, pm, pl);
    k_combine<2><<<8192, 256, 0, stream>>>(po, pm, pl, ws + OFF_ATT);
  } else {
    k_attn<1><<<512, 256, 0, stream>>>(ws, amask, bm, amflag, po, pm, pl);
  }
  k_oproj<<<512, 256, 0, stream>>>(ws, out);
}

// Round 18
// 128.019 us; speedup vs baseline: 1.0143x; 1.0143x over previous
//
#include <hip/hip_runtime.h>

#define NEGF -3.402823466e38f
#define MASKED_F -3.38953139e38f   // most-negative finite bf16 value, used as masked sentinel
#define LOG2E 1.44269504088896f
#define DEFER_THR 8.0f

typedef __attribute__((ext_vector_type(8))) short bf16x8;
typedef __attribute__((ext_vector_type(4))) float f32x4;
typedef __attribute__((ext_vector_type(4))) unsigned short u16x4;
typedef __attribute__((ext_vector_type(4))) int i32x4;
typedef __attribute__((ext_vector_type(2))) unsigned int u32x2;

__device__ __forceinline__ unsigned short f2bf(float f) {
  unsigned u = __builtin_bit_cast(unsigned, f);
  u += 0x7fffu + ((u >> 16) & 1u);
  return (unsigned short)(u >> 16);
}

#define GLOAD_LDS16(gsrc, ldst)                                                     \
  __builtin_amdgcn_global_load_lds(                                                 \
      (const __attribute__((address_space(1))) void*)(gsrc),                        \
      (__attribute__((address_space(3))) void*)(ldst), 16, 0, 0)

// ws layout in ushort units
#define OFF_QH  0u
#define OFF_KH  2097152u
#define OFF_W   4194304u      // 4 x 65536 (Wq,Wk,Wv,Wo) bf16
#define OFF_QP  4456448u      // [B,H,S,D] bf16, pre-scaled by log2e/8
#define OFF_KP  6553600u      // [B,H,S,D] bf16
#define OFF_VT  8650752u      // [B,H,D,S] bf16 (V transposed)
#define OFF_ATT 10747904u     // [B,S,256] bf16
#define OFF_BM  12845056u     // [B][32][2048] u64 align bitmap (2 MB = 1048576 ushorts)
#define OFF_FLAG 13893632u    // int flag: amask has any nonzero
#define USHORT_USED 13893664u // end (64B-aligned past flag)

// ---------------- f32 -> bf16 conversion of inputs (+ flag reset) ----------------
__global__ __launch_bounds__(256) void k_convert(
    const float* __restrict__ qh, const float* __restrict__ kh,
    const float* __restrict__ w0, const float* __restrict__ w1,
    const float* __restrict__ w2, const float* __restrict__ w3,
    unsigned short* __restrict__ dst, int* __restrict__ flag) {
  int v = blockIdx.x * 256 + threadIdx.x;   // vector-of-4 index
  if (v == 0) *flag = 0;                    // reset before k_maskaux (stream-ordered)
  const float* src;
  if (v < 524288)       src = qh + (size_t)v * 4;
  else if (v < 1048576) src = kh + ((size_t)v - 524288) * 4;
  else {
    int t = v - 1048576;                    // 0 .. 65535
    int which = t >> 14;
    const float* w = (which == 0) ? w0 : (which == 1) ? w1 : (which == 2) ? w2 : w3;
    src = w + (size_t)(t & 16383) * 4;
  }
  f32x4 x = *(const f32x4*)src;
  u16x4 o;
  o[0] = f2bf(x[0]); o[1] = f2bf(x[1]); o[2] = f2bf(x[2]); o[3] = f2bf(x[3]);
  *(u16x4*)(dst + (size_t)v * 4) = o;
}

// ---------------- fused align bitpack (k-split across waves) + amask check ----------------
// blocks 0..1023: word-quad g = bid*64 + lane (q4 = g&511, k64 = (g>>9)&31, b = g>>14).
//   Wave ks handles k-rows ks*16..ks*16+15 (16 x i32x4, 1 KB/row per wave, coalesced),
//   partials OR-combined via LDS; thread (ks,lane) stores final word j=ks.
// blocks 1024..2047: OR-reduce amask, set flag if any nonzero.
__global__ __launch_bounds__(256) void k_maskaux(const int* __restrict__ al,
    const float* __restrict__ am, unsigned long long* __restrict__ bm,
    int* __restrict__ flag) {
  __shared__ unsigned long long P[4][64][4];   // [ks][lane][quad j] = 8 KB
  int bid = blockIdx.x;
  if (bid < 1024) {
    int lane = threadIdx.x & 63, ks = threadIdx.x >> 6;
    int g = bid * 64 + lane;                 // word-quad index, 0..65535
    int q4 = g & 511, k64 = (g >> 9) & 31, b = g >> 14;
    const int* base = al + ((size_t)(b * 2048 + k64 * 64 + ks * 16)) * 2048 + q4 * 4;
    unsigned long long w0 = 0, w1 = 0, w2 = 0, w3 = 0;
#pragma unroll
    for (int k = 0; k < 16; ++k) {
      i32x4 v = *(const i32x4*)(base + (size_t)k * 2048);
      unsigned long long bit = 1ull << (ks * 16 + k);
      if (v[0] != 0) w0 |= bit;
      if (v[1] != 0) w1 |= bit;
      if (v[2] != 0) w2 |= bit;
      if (v[3] != 0) w3 |= bit;
    }
    P[ks][lane][0] = w0; P[ks][lane][1] = w1; P[ks][lane][2] = w2; P[ks][lane][3] = w3;
    __syncthreads();
    // thread (ks,lane) combines quad element j = ks of word-quad (bid*64+lane)
    unsigned long long word = P[0][lane][ks] | P[1][lane][ks] |
                              P[2][lane][ks] | P[3][lane][ks];
    bm[((size_t)b * 65536 + k64 * 2048 + q4 * 4) + ks] = word;
  } else {
    const f32x4* p = (const f32x4*)am;      // 4,194,304 f32x4 total
    size_t tid = (size_t)(bid - 1024) * 256 + threadIdx.x;   // 0..262143
    unsigned nz = 0;
#pragma unroll
    for (int j = 0; j < 16; ++j) {
      f32x4 v = p[tid + (size_t)j * 262144];
      nz |= (v[0] != 0.f) | (v[1] != 0.f) | (v[2] != 0.f) | (v[3] != 0.f);
    }
    if (__any(nz)) {
      if ((threadIdx.x & 63) == 0) atomicOr(flag, 1);
    }
  }
}

// ---------------- QKV projections ----------------
__global__ __launch_bounds__(256) void k_proj(unsigned short* __restrict__ ws) {
  int bid = blockIdx.x;
  int mat = bid / 512;            // 0=Q 1=K 2=V
  int rem = bid - mat * 512;
  int mt = rem >> 2, nt = rem & 3;
  int tid = threadIdx.x, w = tid >> 6, lane = tid & 63;
  int l15 = lane & 15, l4 = lane >> 4;

  const unsigned short* X = ws + (mat == 0 ? OFF_QH : OFF_KH);
  const unsigned short* W = ws + OFF_W + (size_t)mat * 65536;

  int i0 = mt * 64 + w * 16;
  int arow = i0 + l15;
  int koff = l4 * 8;

  f32x4 acc[4] = {};
  for (int ks = 0; ks < 8; ++ks) {
    bf16x8 a = *(const bf16x8*)(X + (size_t)arow * 256 + ks * 32 + koff);
#pragma unroll
    for (int ct = 0; ct < 4; ++ct) {
      bf16x8 bb = *(const bf16x8*)(W + (size_t)(nt * 64 + ct * 16 + l15) * 256 + ks * 32 + koff);
      acc[ct] = __builtin_amdgcn_mfma_f32_16x16x32_bf16(a, bb, acc[ct], 0, 0, 0);
    }
  }

  unsigned short* Qp = ws + OFF_QP;
  unsigned short* Kp = ws + OFF_KP;
  unsigned short* Vt = ws + OFF_VT;
  int rbase = i0 + l4 * 4;
#pragma unroll
  for (int ct = 0; ct < 4; ++ct) {
#pragma unroll
    for (int r = 0; r < 4; ++r) {
      int row = rbase + r;
      int b = row >> 11, s = row & 2047;
      int d = ct * 16 + l15;
      float v = acc[ct][r];
      if (mat == 0)      Qp[((size_t)(b * 4 + nt) * 2048 + s) * 64 + d] = f2bf(v * (0.125f * LOG2E));
      else if (mat == 1) Kp[((size_t)(b * 4 + nt) * 2048 + s) * 64 + d] = f2bf(v);
      else               Vt[((size_t)(b * 4 + nt) * 64 + d) * 2048 + s] = f2bf(v);
    }
  }
}

// ---------------- fused masked flash attention ----------------
// swapped QK^T: sfr[kt][r] = S[k = kk + kt*16 + l4*4 + r][q = q0 + l15]
// Mask loads issued BEFORE staging loads (vmcnt FIFO); align-mask applied
// AFTER exp2 by zeroing e. XCD-aware bijective block swizzle.
template <int NS>
__global__ __launch_bounds__(256) void k_attn(unsigned short* __restrict__ ws,
    const float* __restrict__ am, const unsigned long long* __restrict__ bm,
    const int* __restrict__ amflag,
    float* __restrict__ po, float* __restrict__ pm, float* __restrict__ pl) {
  constexpr int LOG = (NS == 4) ? 2 : (NS == 2) ? 1 : 0;
  constexpr int SPAN = 2048 / NS;

  __shared__ __align__(16) unsigned short Kb[2][4096];   // [64 krow][64 d] swizzled
  __shared__ __align__(16) unsigned short Vb[2][4096];   // [64 d][64 k] swizzled
  __shared__ __align__(16) unsigned short plds[4][1024]; // per-wave 16x64 P, swizzled

  // XCD swizzle: grid % 8 == 0 (512*NS). Physical p runs on XCD p%8;
  // logical bid = (p%8)*(grid/8) + p/8 gives each XCD a contiguous chunk.
  int cpx = (int)gridDim.x >> 3;
  int bid = ((int)blockIdx.x & 7) * cpx + ((int)blockIdx.x >> 3);

  int sp = bid & (NS - 1);
  int qt = (bid >> LOG) & 31;
  int bh = bid >> (LOG + 5);
  int b = bh >> 2, h = bh & 3;
  int tid = threadIdx.x, w = tid >> 6, lane = tid & 63;
  int l15 = lane & 15, l4 = lane >> 4;
  int q0 = qt * 64 + w * 16;

  const bool hasam = (*amflag != 0);   // wave-uniform

  const unsigned short* Qp = ws + OFF_QP;
  const unsigned short* Kp = ws + OFF_KP + (size_t)bh * 2048 * 64;
  const unsigned short* Vt = ws + OFF_VT + (size_t)bh * 64 * 2048;
  const float* amq = am + ((size_t)(b * 2048 + q0 + l15)) * 2048;     // this lane's q-row
  const unsigned long long* bmq = bm + (size_t)b * 65536 + q0 + l15;  // + k64*2048

  // staging geometry: lane i covers row (c*8 + i>>3), global col chunk (i&7)^(i>>3)
  int srow = lane >> 3;
  int scol = ((lane & 7) ^ srow) * 8;
  int c0 = w * 2;

  bf16x8 qf0 = *(const bf16x8*)(Qp + ((size_t)bh * 2048 + q0 + l15) * 64 + l4 * 8);
  bf16x8 qf1 = *(const bf16x8*)(Qp + ((size_t)bh * 2048 + q0 + l15) * 64 + 32 + l4 * 8);

  f32x4 o[4] = {};
  float mrun = -__builtin_inff();
  float lpart = 0.f;                // per-lane partial sum (this lane's k-subset of row q=l15)
  int s0 = l4 * 4;

  int kk0 = sp * SPAN;
#pragma unroll
  for (int c2 = 0; c2 < 2; ++c2) {
    int c = c0 + c2;
    GLOAD_LDS16(Kp + (size_t)(kk0 + c * 8 + srow) * 64 + scol, &Kb[0][c * 512]);
    GLOAD_LDS16(Vt + (size_t)(c * 8 + srow) * 2048 + kk0 + scol, &Vb[0][c * 512]);
  }
  __syncthreads();

  int cur = 0;
  for (int kk = kk0; kk < kk0 + SPAN; kk += 64) {
    // ---- mask inputs FIRST (oldest in vmcnt FIFO -> consume waits only these) ----
    unsigned long long wbits = bmq[(size_t)(kk >> 6) * 2048];
    f32x4 a0{}, a1{}, a2{}, a3{};
    if (hasam) {
      a0 = *(const f32x4*)(amq + kk + 0 * 16 + s0);
      a1 = *(const f32x4*)(amq + kk + 1 * 16 + s0);
      a2 = *(const f32x4*)(amq + kk + 2 * 16 + s0);
      a3 = *(const f32x4*)(amq + kk + 3 * 16 + s0);
    }
    // ---- stage next tile (stays in flight across whole iteration) ----
    if (kk + 64 < kk0 + SPAN) {
#pragma unroll
      for (int c2 = 0; c2 < 2; ++c2) {
        int c = c0 + c2;
        GLOAD_LDS16(Kp + (size_t)(kk + 64 + c * 8 + srow) * 64 + scol, &Kb[cur ^ 1][c * 512]);
        GLOAD_LDS16(Vt + (size_t)(c * 8 + srow) * 2048 + (kk + 64) + scol, &Vb[cur ^ 1][c * 512]);
      }
    }

    // ---- scores (log2 domain, swapped): S^T = K @ Q^T ----
    f32x4 sfr[4];
    __builtin_amdgcn_s_setprio(1);
#pragma unroll
    for (int kt = 0; kt < 4; ++kt) {
      int row = kt * 16 + l15;
      int sw = l15 & 7;
      bf16x8 k0 = *(const bf16x8*)&Kb[cur][row * 64 + ((l4 ^ sw) * 8)];
      bf16x8 k1 = *(const bf16x8*)&Kb[cur][row * 64 + (((4 + l4) ^ sw) * 8)];
      f32x4 acc = {};
      acc = __builtin_amdgcn_mfma_f32_16x16x32_bf16(k0, qf0, acc, 0, 0, 0);
      acc = __builtin_amdgcn_mfma_f32_16x16x32_bf16(k1, qf1, acc, 0, 0, 0);
      sfr[kt] = acc;
    }
    __builtin_amdgcn_s_setprio(0);

    // ---- amask add (slow path only) ----
    if (hasam) {
#pragma unroll
      for (int kt = 0; kt < 4; ++kt) {
        f32x4 a = (kt == 0) ? a0 : (kt == 1) ? a1 : (kt == 2) ? a2 : a3;
#pragma unroll
        for (int r = 0; r < 4; ++r) sfr[kt][r] = fmaf(a[r], LOG2E, sfr[kt][r]);
      }
    }

    // ---- per-lane row max over UNMASKED scores (valid common M) ----
    float pmax = sfr[0][0];
#pragma unroll
    for (int kt = 0; kt < 4; ++kt)
#pragma unroll
      for (int r = 0; r < 4; ++r) pmax = fmaxf(pmax, sfr[kt][r]);
    pmax = fmaxf(pmax, __shfl_xor(pmax, 16));
    pmax = fmaxf(pmax, __shfl_xor(pmax, 32));

    // ---- defer-max: rescale only when max grew past threshold ----
    if (__any(pmax > mrun + DEFER_THR)) {
      float mnew = fmaxf(mrun, pmax);
      float sfac = exp2f(mrun - mnew);
      mrun = mnew;
      lpart *= sfac;
#pragma unroll
      for (int r = 0; r < 4; ++r) {
        float sf = __shfl(sfac, l4 * 4 + r);
        o[0][r] *= sf; o[1][r] *= sf; o[2][r] *= sf; o[3][r] *= sf;
      }
    }

    // ---- exp2, mask-by-zero, partial sum, P-pack ----
    unsigned blo = (unsigned)wbits, bhi = (unsigned)(wbits >> 32);
    float ls = 0.f;
#pragma unroll
    for (int kt = 0; kt < 4; ++kt) {
      unsigned tbits = ((kt & 2) ? bhi : blo) >> ((kt & 1) ? 16 + s0 : s0);
      float em[4];
#pragma unroll
      for (int r = 0; r < 4; ++r) {
        float e = exp2f(sfr[kt][r] - mrun);
        unsigned keep = 0u - ((tbits >> r) & 1u);   // all-ones or zero
        em[r] = __builtin_bit_cast(float, __builtin_bit_cast(unsigned, e) & keep);
        ls += em[r];
      }
      unsigned lo, hi;
      asm("v_cvt_pk_bf16_f32 %0, %1, %2" : "=v"(lo) : "v"(em[0]), "v"(em[1]));
      asm("v_cvt_pk_bf16_f32 %0, %1, %2" : "=v"(hi) : "v"(em[2]), "v"(em[3]));
      int chunk = kt * 2 + (l4 >> 1);
      int addr = l15 * 64 + (((chunk) ^ (l15 & 7)) << 3) + ((l4 & 1) << 2);
      u32x2 pk; pk[0] = lo; pk[1] = hi;
      *(u32x2*)&plds[w][addr] = pk;
    }
    lpart += ls;

    // ---- PV: O += P @ V from LDS ----
    __builtin_amdgcn_s_setprio(1);
#pragma unroll
    for (int ks = 0; ks < 2; ++ks) {
      int chnk = ks * 4 + l4;
      bf16x8 pa = *(const bf16x8*)&plds[w][l15 * 64 + ((chnk ^ (l15 & 7)) << 3)];
#pragma unroll
      for (int dt = 0; dt < 4; ++dt) {
        int row = dt * 16 + l15;
        bf16x8 vf = *(const bf16x8*)&Vb[cur][row * 64 + (((ks * 4 + l4) ^ (l15 & 7)) * 8)];
        o[dt] = __builtin_amdgcn_mfma_f32_16x16x32_bf16(pa, vf, o[dt], 0, 0, 0);
      }
    }
    __builtin_amdgcn_s_setprio(0);

    __syncthreads();   // drains vmcnt (stage done) + guards buffer swap
    cur ^= 1;
  }

  // ---- epilogue: reduce per-lane partial sums across l4 ----
  float lsum = lpart;
  lsum += __shfl_xor(lsum, 16);
  lsum += __shfl_xor(lsum, 32);

  if constexpr (NS == 1) {
    unsigned short* attnb = ws + OFF_ATT;
#pragma unroll
    for (int r = 0; r < 4; ++r) {
      float inv = 1.0f / __shfl(lsum, l4 * 4 + r);
      int qrow = q0 + l4 * 4 + r;
#pragma unroll
      for (int dt = 0; dt < 4; ++dt)
        attnb[(size_t)(b * 2048 + qrow) * 256 + h * 64 + dt * 16 + l15] = f2bf(o[dt][r] * inv);
    }
  } else {
    float* pob = po + (((size_t)sp * 16 + bh) * 2048) * 64;
#pragma unroll
    for (int r = 0; r < 4; ++r) {
      int qrow = q0 + l4 * 4 + r;
#pragma unroll
      for (int dt = 0; dt < 4; ++dt)
        pob[(size_t)qrow * 64 + dt * 16 + l15] = o[dt][r];
    }
    if (l4 == 0) {
      pm[(size_t)sp * 32768 + bh * 2048 + q0 + l15] = mrun;
      pl[(size_t)sp * 32768 + bh * 2048 + q0 + l15] = lsum;
    }
  }
}

// ---------------- combine K-splits (log2 domain weights) ----------------
template <int NS>
__global__ __launch_bounds__(256) void k_combine(const float* __restrict__ po,
    const float* __restrict__ pm, const float* __restrict__ pl,
    unsigned short* __restrict__ attnb) {
  int t = blockIdx.x * 256 + threadIdx.x;
  int d = t & 63;
  int row = t >> 6;                 // bh*2048 + qrow, 0..32767

  float m[NS], l[NS];
  float M = -__builtin_inff();
#pragma unroll
  for (int sp = 0; sp < NS; ++sp) {
    m[sp] = pm[(size_t)sp * 32768 + row];
    l[sp] = pl[(size_t)sp * 32768 + row];
    M = fmaxf(M, m[sp]);
  }
  float denom = 0.f, acc = 0.f;
#pragma unroll
  for (int sp = 0; sp < NS; ++sp) {
    float wgt = exp2f(m[sp] - M);
    denom += l[sp] * wgt;
    acc += po[((size_t)sp * 32768 + row) * 64 + d] * wgt;
  }
  float val = acc / denom;
  int bh = row >> 11, qrow = row & 2047;
  int b = bh >> 2, h = bh & 3;
  attnb[((size_t)(b * 2048 + qrow)) * 256 + h * 64 + d] = f2bf(val);
}

// ---------------- output projection ----------------
__global__ __launch_bounds__(256) void k_oproj(const unsigned short* __restrict__ ws,
                                               float* __restrict__ out) {
  int bid = blockIdx.x;
  int mt = bid >> 2, nt = bid & 3;
  int tid = threadIdx.x, w = tid >> 6, lane = tid & 63;
  int l15 = lane & 15, l4 = lane >> 4;

  const unsigned short* A = ws + OFF_ATT;
  const unsigned short* W = ws + OFF_W + 3u * 65536u;   // Wo
  int i0 = mt * 64 + w * 16;

  f32x4 acc[4] = {};
  for (int ks = 0; ks < 8; ++ks) {
    bf16x8 a = *(const bf16x8*)(A + (size_t)(i0 + l15) * 256 + ks * 32 + l4 * 8);
#pragma unroll
    for (int ct = 0; ct < 4; ++ct) {
      bf16x8 bb = *(const bf16x8*)(W + (size_t)(nt * 64 + ct * 16 + l15) * 256 + ks * 32 + l4 * 8);
      acc[ct] = __builtin_amdgcn_mfma_f32_16x16x32_bf16(a, bb, acc[ct], 0, 0, 0);
    }
  }
#pragma unroll
  for (int ct = 0; ct < 4; ++ct)
#pragma unroll
    for (int r = 0; r < 4; ++r)
      out[(size_t)(i0 + l4 * 4 + r) * 256 + nt * 64 + ct * 16 + l15] = acc[ct][r];
}

extern "C" void kernel_launch(void* const* d_in, const int* in_sizes, int n_in,
                              void* d_out, int out_size, void* d_ws, size_t ws_size,
                              hipStream_t stream) {
  const float* qh = (const float*)d_in[0];
  const float* kh = (const float*)d_in[1];
  const float* amask = (const float*)d_in[2];
  const int* alignm = (const int*)d_in[3];
  const float* Wq = (const float*)d_in[4];
  const float* Wk = (const float*)d_in[5];
  const float* Wv = (const float*)d_in[6];
  const float* Wo = (const float*)d_in[7];
  float* out = (float*)d_out;
  unsigned short* ws = (unsigned short*)d_ws;
  unsigned long long* bm = (unsigned long long*)(ws + OFF_BM);
  int* amflag = (int*)(ws + OFF_FLAG);

  k_convert<<<4352, 256, 0, stream>>>(qh, kh, Wq, Wk, Wv, Wo, ws, amflag);
  k_maskaux<<<2048, 256, 0, stream>>>(alignm, amask, bm, amflag);
  k_proj<<<1536, 256, 0, stream>>>(ws);

  size_t avail_f = (ws_size > (size_t)USHORT_USED * 2)
                       ? (ws_size - (size_t)USHORT_USED * 2) / 4 : 0;
  auto need = [](int ns) { return (size_t)ns * (2097152 + 65536); };
  int NSv = (avail_f >= need(2)) ? 2 : 1;
  float* po = (float*)(ws + USHORT_USED);
  float* pm = po + (size_t)NSv * 2097152;
  float* pl = pm + (size_t)NSv * 32768;

  if (NSv == 2) {
    k_attn<2><<<1024, 256, 0, stream>>>(ws, amask, bm, amflag, po, pm, pl);
    k_combine<2><<<8192, 256, 0, stream>>>(po, pm, pl, ws + OFF_ATT);
  } else {
    k_attn<1><<<512, 256, 0, stream>>>(ws, amask, bm, amflag, po, pm, pl);
  }
  k_oproj<<<512, 256, 0, stream>>>(ws, out);
}